// Round 5
// baseline (1629.513 us; speedup 1.0000x reference)
//
#include <hip/hip_runtime.h>

#define BB 256
#define TT 1024
#define II 128
#define GG 512   // 2C
#define CC 256
#define L2E 1.44269504f

typedef _Float16 f16;
typedef _Float16 h8_t __attribute__((ext_vector_type(8)));
typedef float f4_t __attribute__((ext_vector_type(4)));
typedef unsigned short ushort_t;
typedef unsigned short us4_t __attribute__((ext_vector_type(4)));

static __device__ __forceinline__ float fast_rcp(float x) {
#if __has_builtin(__builtin_amdgcn_rcpf)
    return __builtin_amdgcn_rcpf(x);
#else
    return 1.f / x;
#endif
}
static __device__ __forceinline__ float fast_exp2(float x) {
#if __has_builtin(__builtin_amdgcn_exp2f)
    return __builtin_amdgcn_exp2f(x);
#else
    return exp2f(x);
#endif
}

// producer->consumer flags: [0..2047] per-mtile ready, [2048] completion counter.
// Zeroed by kt_transpose (kernel boundary orders it before the fused kernel).
__device__ unsigned g_flags[2049];

// ---- kernel 1: Kt[n][k] = f16(kernel[k][n])  (128x512 -> 512x128), + zero flags ----
__global__ void kt_transpose(const float* __restrict__ kin, f16* __restrict__ kt) {
    int idx = blockIdx.x * 256 + threadIdx.x;   // 65536 total
    if (idx < 2049) g_flags[idx] = 0u;
    int k = idx >> 9;
    int n = idx & 511;
    kt[n * II + k] = (f16)kin[k * GG + n];
}

// ---- fused kernel: blocks 0..15 = recurrence (dispatch first -> dedicated CUs),
//      blocks 16..2063 = xz GEMM tiles running CONCURRENTLY on the other CUs.
// xz layout: xz[((t*16 + g)*512 + col)*16 + bl], batch b = g*16 + bl.
// janet group g needs mtile 2t + (g>>3) for step t; gated by g_flags[mtile]
// (agent-scope release by producer, acquire by consumer). Once counter==2048,
// consumer latches alldone and skips all atomics. 48KB dynamic LDS forces
// 1 block/CU so gemm blocks never share a CU with recurrence blocks.
#define STEP(T, PF, PP, HRD, HWR) do {                                               \
    h8_t af[8];                                                                      \
    _Pragma("unroll") for (int kt = 0; kt < 4; ++kt)                                 \
        af[kt] = *(const h8_t*)((HRD) + lm * 264 + kt * 32 + q * 8);                 \
    f4_t acc[4];                                                                     \
    _Pragma("unroll") for (int ni = 0; ni < 4; ++ni) {                               \
        f4_t av;                                                                     \
        _Pragma("unroll") for (int r = 0; r < 4; ++r) {                              \
            ushort_t u = (PF)[ni * 4 + r];                                           \
            f16 hv = *(f16*)&u;                                                      \
            av[r] = (float)hv;                                                       \
        }                                                                            \
        acc[ni] = av;                                                                \
    }                                                                                \
    if ((T) + 2 < TT) {                                                              \
        if (!alldone) {                                                              \
            unsigned cn = __hip_atomic_load(&g_flags[2048], __ATOMIC_ACQUIRE,        \
                                            __HIP_MEMORY_SCOPE_AGENT);               \
            if (cn == 2048u) { alldone = true; }                                     \
            else {                                                                   \
                unsigned ff;                                                         \
                do {                                                                 \
                    ff = __hip_atomic_load(&g_flags[2 * ((T) + 2) + gh],             \
                                           __ATOMIC_ACQUIRE,                         \
                                           __HIP_MEMORY_SCOPE_AGENT);                \
                    if (!ff) __builtin_amdgcn_s_sleep(8);                            \
                } while (!ff);                                                       \
            }                                                                        \
        }                                                                            \
        _Pragma("unroll") for (int ni = 0; ni < 4; ++ni) {                           \
            us4_t v = *(const us4_t*)((PP) + ni * 2048);                             \
            (PF)[ni * 4 + 0] = v[0];                                                 \
            (PF)[ni * 4 + 1] = v[1];                                                 \
            (PF)[ni * 4 + 2] = v[2];                                                 \
            (PF)[ni * 4 + 3] = v[3];                                                 \
        }                                                                            \
        (PP) += 2 * 131072;                                                          \
    }                                                                                \
    /* low half: kt 0..3, pair-major */                                              \
    _Pragma("unroll") for (int kt = 0; kt < 4; ++kt) {                               \
        acc[0] = __builtin_amdgcn_mfma_f32_16x16x32_f16(af[kt], bw[0][kt], acc[0], 0, 0, 0); \
        acc[2] = __builtin_amdgcn_mfma_f32_16x16x32_f16(af[kt], bw[2][kt], acc[2], 0, 0, 0); \
    }                                                                                \
    _Pragma("unroll") for (int kt = 0; kt < 4; ++kt) {                               \
        acc[1] = __builtin_amdgcn_mfma_f32_16x16x32_f16(af[kt], bw[1][kt], acc[1], 0, 0, 0); \
        acc[3] = __builtin_amdgcn_mfma_f32_16x16x32_f16(af[kt], bw[3][kt], acc[3], 0, 0, 0); \
    }                                                                                \
    asm volatile("s_waitcnt lgkmcnt(0)\n\ts_barrier" ::: "memory");  /* BAR_a */     \
    _Pragma("unroll") for (int kt = 4; kt < 8; ++kt)                                 \
        af[kt] = *(const h8_t*)((HRD) + lm * 264 + kt * 32 + q * 8);                 \
    /* high half: kt 4..7, pair-major (acc0/2 first so valu0 can start early) */     \
    _Pragma("unroll") for (int kt = 4; kt < 8; ++kt) {                               \
        acc[0] = __builtin_amdgcn_mfma_f32_16x16x32_f16(af[kt], bw[0][kt], acc[0], 0, 0, 0); \
        acc[2] = __builtin_amdgcn_mfma_f32_16x16x32_f16(af[kt], bw[2][kt], acc[2], 0, 0, 0); \
    }                                                                                \
    _Pragma("unroll") for (int kt = 4; kt < 8; ++kt) {                               \
        acc[1] = __builtin_amdgcn_mfma_f32_16x16x32_f16(af[kt], bw[1][kt], acc[1], 0, 0, 0); \
        acc[3] = __builtin_amdgcn_mfma_f32_16x16x32_f16(af[kt], bw[3][kt], acc[3], 0, 0, 0); \
    }                                                                                \
    /* pair 0 sigmoid/tanh + write h_low(T+1) */                                     \
    _Pragma("unroll") for (int r = 0; r < 4; ++r) {                                  \
        float zf = acc[0][r];                                                        \
        float zg = acc[2][r];                                                        \
        float ef = fast_exp2(-zf);                                                   \
        float eg = fast_exp2(-fabsf(zg));                                            \
        float t1 = (zg < 0.f) ? -ef : ef;                                            \
        float cv = cst[0][r];                                                        \
        float num = fmaf(cv, eg, cv) + fmaf(-t1, eg, t1);                            \
        float den = (1.f + ef) * (1.f + eg);                                         \
        cst[0][r] = num * fast_rcp(den);                                             \
        (HWR)[(q * 4 + r) * 264 + wave * 16 + lm] = (f16)cst[0][r];                  \
    }                                                                                \
    asm volatile("s_waitcnt lgkmcnt(0)\n\ts_barrier" ::: "memory");  /* BAR_b */     \
    /* pair 1 sigmoid/tanh + write h_high(T+1); next step's low MFMAs follow */      \
    _Pragma("unroll") for (int r = 0; r < 4; ++r) {                                  \
        float zf = acc[1][r];                                                        \
        float zg = acc[3][r];                                                        \
        float ef = fast_exp2(-zf);                                                   \
        float eg = fast_exp2(-fabsf(zg));                                            \
        float t1 = (zg < 0.f) ? -ef : ef;                                            \
        float cv = cst[1][r];                                                        \
        float num = fmaf(cv, eg, cv) + fmaf(-t1, eg, t1);                            \
        float den = (1.f + ef) * (1.f + eg);                                         \
        cst[1][r] = num * fast_rcp(den);                                             \
        (HWR)[(q * 4 + r) * 264 + (wave + 8) * 16 + lm] = (f16)cst[1][r];            \
    }                                                                                \
} while (0)

__global__ __launch_bounds__(512, 2)
void janet_fused(const float* __restrict__ x, const f16* __restrict__ kt,
                 const float* __restrict__ bias, ushort_t* __restrict__ xz,
                 const float* __restrict__ rk, const float* __restrict__ dw,
                 const float* __restrict__ db, float* __restrict__ out) {
    const int tid = threadIdx.x;
    const int wave = tid >> 6;
    const int lane = tid & 63;
    const int lm = lane & 15;
    const int q  = lane >> 4;

    if (blockIdx.x >= 16) {
        // ================= GEMM path (one 128-row x 512-col tile) =================
        const long mtile = blockIdx.x - 16;   // 0..2047
        const int wm = (wave & 1) * 64;
        const int wn = (wave >> 1) * 128;     // 0,128,256,384

        f4_t acc[4][8];
#pragma unroll
        for (int mi = 0; mi < 4; ++mi)
#pragma unroll
            for (int nj = 0; nj < 8; ++nj)
                acc[mi][nj] = (f4_t){0.f, 0.f, 0.f, 0.f};

#pragma unroll
        for (int kc = 0; kc < 4; ++kc) {
            h8_t a[4], bf[8];
#pragma unroll
            for (int mi = 0; mi < 4; ++mi) {
                const int rowm = (int)(mtile * 128) + wm + mi * 16 + lm;   // m'
                const int b  = rowm & 255;
                const int tt = rowm >> 8;
                const float* ap = x + (size_t)b * (TT * II) + (size_t)tt * II + kc * 32 + q * 8;
                f4_t p0 = *(const f4_t*)ap;
                f4_t p1 = *(const f4_t*)(ap + 4);
                h8_t tv;
                tv[0] = (f16)p0[0]; tv[1] = (f16)p0[1]; tv[2] = (f16)p0[2]; tv[3] = (f16)p0[3];
                tv[4] = (f16)p1[0]; tv[5] = (f16)p1[1]; tv[6] = (f16)p1[2]; tv[7] = (f16)p1[3];
                a[mi] = tv;
            }
#pragma unroll
            for (int nj = 0; nj < 8; ++nj) {
                const f16* bp = kt + (size_t)(wn + nj * 16 + lm) * II + kc * 32 + q * 8;
                bf[nj] = *(const h8_t*)bp;
            }
#pragma unroll
            for (int mi = 0; mi < 4; ++mi)
#pragma unroll
                for (int nj = 0; nj < 8; ++nj)
                    acc[mi][nj] = __builtin_amdgcn_mfma_f32_16x16x32_f16(a[mi], bf[nj], acc[mi][nj], 0, 0, 0);
        }

        // epilogue: C/D layout col=lane&15, row=(lane>>4)*4+reg (m89); coalesced us4 bursts
#pragma unroll
        for (int mi = 0; mi < 4; ++mi) {
            const int rowm0 = (int)(mtile * 128) + wm + mi * 16 + q * 4;
            const int t  = rowm0 >> 8;
            const int b0 = rowm0 & 255;
            const int gq = b0 >> 4;
#pragma unroll
            for (int nj = 0; nj < 8; ++nj) {
                const int col = wn + nj * 16 + lm;
                const float bv = bias[col];
                const float s  = (col < CC) ? L2E : (2.0f * L2E);
                us4_t v;
#pragma unroll
                for (int r = 0; r < 4; ++r) {
                    f16 hv = (f16)((acc[mi][nj][r] + bv) * s);
                    v[r] = *(ushort_t*)&hv;
                }
                *(us4_t*)(xz + (((size_t)t * 16 + gq) * 512 + col) * 16 + q * 4) = v;
            }
        }

        // publish tile: all block stores done (syncthreads drains vmcnt), then release.
        __syncthreads();
        if (tid == 0) {
            __hip_atomic_store(&g_flags[(int)mtile], 1u, __ATOMIC_RELEASE, __HIP_MEMORY_SCOPE_AGENT);
            __hip_atomic_fetch_add(&g_flags[2048], 1u, __ATOMIC_RELEASE, __HIP_MEMORY_SCOPE_AGENT);
        }
        return;
    }

    // ================= recurrence path (blocks 0..15) =================
    const int g = blockIdx.x;            // batch group: batches g*16 .. g*16+15
    const int gh = g >> 3;               // which half-tile of each mtile pair
    bool alldone = false;

    // resident pre-scaled recurrent weights: bw[ni][kt][j] = s * R[kt*32+q*8+j][(wave+8*ni)*16+lm]
    h8_t bw[4][8];
#pragma unroll
    for (int ni = 0; ni < 4; ++ni) {
        const float s = (ni < 2) ? L2E : (2.0f * L2E);
#pragma unroll
        for (int kt = 0; kt < 8; ++kt) {
            h8_t tv;
#pragma unroll
            for (int j = 0; j < 8; ++j)
                tv[j] = (f16)(s * rk[(size_t)(kt * 32 + q * 8 + j) * GG + (wave + 8 * ni) * 16 + lm]);
            bw[ni][kt] = tv;
        }
    }

    __shared__ __align__(16) f16 hb[2][16][264];
    f16* h0 = &hb[0][0][0];
    f16* h1 = &hb[1][0][0];
    for (int i = tid; i < 2 * 16 * 264; i += 512) ((f16*)hb)[i] = (f16)0.f;

    float cst[2][4];
#pragma unroll
    for (int ni = 0; ni < 2; ++ni)
#pragma unroll
        for (int r = 0; r < 4; ++r) cst[ni][r] = 0.f;

    // wait for t=0 and t=1 tiles of this group's half
    {
        unsigned ff;
        do { ff = __hip_atomic_load(&g_flags[gh], __ATOMIC_ACQUIRE, __HIP_MEMORY_SCOPE_AGENT);
             if (!ff) __builtin_amdgcn_s_sleep(8); } while (!ff);
        do { ff = __hip_atomic_load(&g_flags[2 + gh], __ATOMIC_ACQUIRE, __HIP_MEMORY_SCOPE_AGENT);
             if (!ff) __builtin_amdgcn_s_sleep(8); } while (!ff);
    }

    // per-thread xz base (blocked layout): value(t, b=g*16+q*4+r, col=wave*16+lm+ni*128)
    // at PB[t*131072 + ni*2048 + r]; the 4 r-values are contiguous -> dwordx2 loads.
    const ushort_t* PB = xz + (size_t)g * 8192 + (wave * 16 + lm) * 16 + q * 4;
    const ushort_t* p0 = PB + 2 * 131072;       // refill source for pf0 (t=2,4,...)
    const ushort_t* p1 = PB + 3 * 131072;       // refill source for pf1 (t=3,5,...)

    ushort_t pf0[16], pf1[16];
#pragma unroll
    for (int ni = 0; ni < 4; ++ni) {
        us4_t v0 = *(const us4_t*)(PB + ni * 2048);
        us4_t v1 = *(const us4_t*)(PB + 131072 + ni * 2048);
        pf0[ni * 4 + 0] = v0[0]; pf0[ni * 4 + 1] = v0[1];
        pf0[ni * 4 + 2] = v0[2]; pf0[ni * 4 + 3] = v0[3];
        pf1[ni * 4 + 0] = v1[0]; pf1[ni * 4 + 1] = v1[1];
        pf1[ni * 4 + 2] = v1[2]; pf1[ni * 4 + 3] = v1[3];
    }
    __syncthreads();

#pragma unroll 1
    for (int t = 0; t < TT; t += 2) {
        STEP(t,     pf0, p0, h0, h1);
        STEP(t + 1, pf1, p1, h1, h0);
    }

    // final dense: out[b] = h_final @ dense_w + db
    __shared__ float hf[16][256];
#pragma unroll
    for (int ni = 0; ni < 2; ++ni)
#pragma unroll
        for (int r = 0; r < 4; ++r)
            hf[q * 4 + r][(wave + 8 * ni) * 16 + lm] = cst[ni][r];
    __syncthreads();
    if (tid < 160) {
        const int bi = tid / 10, o = tid % 10;
        float acc = db[o];
#pragma unroll 8
        for (int cc = 0; cc < CC; ++cc) acc = fmaf(hf[bi][cc], dw[cc * 10 + o], acc);
        out[(g * 16 + bi) * 10 + o] = acc;
    }
}

// ---- guard ----
__global__ void ws_too_small(float* out, float wssz) {
    int i = blockIdx.x * 256 + threadIdx.x;
    if (i < BB * 10) out[i] = (i == 0) ? wssz : 0.f;
}

extern "C" void kernel_launch(void* const* d_in, const int* in_sizes, int n_in,
                              void* d_out, int out_size, void* d_ws, size_t ws_size,
                              hipStream_t stream) {
    const float* x   = (const float*)d_in[0];
    const float* kin = (const float*)d_in[1];
    const float* rk  = (const float*)d_in[2];
    const float* rb  = (const float*)d_in[3];
    const float* dw  = (const float*)d_in[4];
    const float* db  = (const float*)d_in[5];
    float* out = (float*)d_out;

    const size_t xz_bytes = (size_t)BB * TT * GG * 2;   // 268,435,456
    const size_t kt_bytes = (size_t)GG * II * 2;        // 131,072
    if (ws_size < xz_bytes + kt_bytes) {
        ws_too_small<<<10, 256, 0, stream>>>(out, (float)ws_size);
        return;
    }

    ushort_t* xz = (ushort_t*)d_ws;
    f16* kt = (f16*)((char*)d_ws + xz_bytes);

    kt_transpose<<<256, 256, 0, stream>>>(kin, kt);
    // 48KB dynamic LDS (+33KB static) -> 1 block/CU: recurrence blocks get
    // dedicated CUs; gemm blocks fill the remaining ~240 CUs concurrently.
    janet_fused<<<2064, 512, 49152, stream>>>(x, kt, rb, xz, rk, dw, db, out);
}

// Round 6
// 1429.675 us; speedup vs baseline: 1.1398x; 1.1398x over previous
//
#include <hip/hip_runtime.h>

#define BB 256
#define TT 1024
#define II 128
#define GG 512   // 2C
#define CC 256
#define L2E 1.44269504f

typedef _Float16 f16;
typedef _Float16 h8_t __attribute__((ext_vector_type(8)));
typedef float f4_t __attribute__((ext_vector_type(4)));
typedef unsigned short ushort_t;
typedef unsigned short us4_t __attribute__((ext_vector_type(4)));

static __device__ __forceinline__ float fast_rcp(float x) {
#if __has_builtin(__builtin_amdgcn_rcpf)
    return __builtin_amdgcn_rcpf(x);
#else
    return 1.f / x;
#endif
}
static __device__ __forceinline__ float fast_exp2(float x) {
#if __has_builtin(__builtin_amdgcn_exp2f)
    return __builtin_amdgcn_exp2f(x);
#else
    return exp2f(x);
#endif
}

// producer->consumer flags: [0..2047] per-mtile ready, [2048] completion counter.
// Zeroed by kt_transpose (kernel boundary orders it before the fused kernel).
__device__ unsigned g_flags[2049];

// ---- kernel 1: Kt[n][k] = f16(kernel[k][n])  (128x512 -> 512x128), + zero flags ----
__global__ void kt_transpose(const float* __restrict__ kin, f16* __restrict__ kt) {
    int idx = blockIdx.x * 256 + threadIdx.x;   // 65536 total
    if (idx < 2049) g_flags[idx] = 0u;
    int k = idx >> 9;
    int n = idx & 511;
    kt[n * II + k] = (f16)kin[k * GG + n];
}

// ---- fused kernel: blocks 0..15 = recurrence (dispatch first -> dedicated CUs),
//      blocks 16..2063 = xz GEMM tiles running CONCURRENTLY on the other CUs.
// xz layout: xz[((t*16 + g)*512 + col)*16 + bl], batch b = g*16 + bl.
// Sync (fixed vs r5): consumer verifies tile flags in 32-step CHUNKS, wave-parallel
// (lane l acquire-loads flag[2(t+2+l)+gh], spin on __all) -> ~20 cyc/step amortized
// instead of a serialized ~600-cyc acquire round-trip EVERY step (r5's regression).
// Steady-state STEP is identical to the r4 split-barrier step.
#define STEP(T, PF, PP, HRD, HWR) do {                                               \
    h8_t af[8];                                                                      \
    _Pragma("unroll") for (int kt = 0; kt < 4; ++kt)                                 \
        af[kt] = *(const h8_t*)((HRD) + lm * 264 + kt * 32 + q * 8);                 \
    f4_t acc[4];                                                                     \
    _Pragma("unroll") for (int ni = 0; ni < 4; ++ni) {                               \
        f4_t av;                                                                     \
        _Pragma("unroll") for (int r = 0; r < 4; ++r) {                              \
            ushort_t u = (PF)[ni * 4 + r];                                           \
            f16 hv = *(f16*)&u;                                                      \
            av[r] = (float)hv;                                                       \
        }                                                                            \
        acc[ni] = av;                                                                \
    }                                                                                \
    if ((T) + 2 < TT) {                                                              \
        _Pragma("unroll") for (int ni = 0; ni < 4; ++ni) {                           \
            us4_t v = *(const us4_t*)((PP) + ni * 2048);                             \
            (PF)[ni * 4 + 0] = v[0];                                                 \
            (PF)[ni * 4 + 1] = v[1];                                                 \
            (PF)[ni * 4 + 2] = v[2];                                                 \
            (PF)[ni * 4 + 3] = v[3];                                                 \
        }                                                                            \
        (PP) += 2 * 131072;                                                          \
    }                                                                                \
    /* low half: kt 0..3, pair-major */                                              \
    _Pragma("unroll") for (int kt = 0; kt < 4; ++kt) {                               \
        acc[0] = __builtin_amdgcn_mfma_f32_16x16x32_f16(af[kt], bw[0][kt], acc[0], 0, 0, 0); \
        acc[2] = __builtin_amdgcn_mfma_f32_16x16x32_f16(af[kt], bw[2][kt], acc[2], 0, 0, 0); \
    }                                                                                \
    _Pragma("unroll") for (int kt = 0; kt < 4; ++kt) {                               \
        acc[1] = __builtin_amdgcn_mfma_f32_16x16x32_f16(af[kt], bw[1][kt], acc[1], 0, 0, 0); \
        acc[3] = __builtin_amdgcn_mfma_f32_16x16x32_f16(af[kt], bw[3][kt], acc[3], 0, 0, 0); \
    }                                                                                \
    asm volatile("s_waitcnt lgkmcnt(0)\n\ts_barrier" ::: "memory");  /* BAR_a */     \
    _Pragma("unroll") for (int kt = 4; kt < 8; ++kt)                                 \
        af[kt] = *(const h8_t*)((HRD) + lm * 264 + kt * 32 + q * 8);                 \
    /* high half: kt 4..7, pair-major (acc0/2 first so valu0 can start early) */     \
    _Pragma("unroll") for (int kt = 4; kt < 8; ++kt) {                               \
        acc[0] = __builtin_amdgcn_mfma_f32_16x16x32_f16(af[kt], bw[0][kt], acc[0], 0, 0, 0); \
        acc[2] = __builtin_amdgcn_mfma_f32_16x16x32_f16(af[kt], bw[2][kt], acc[2], 0, 0, 0); \
    }                                                                                \
    _Pragma("unroll") for (int kt = 4; kt < 8; ++kt) {                               \
        acc[1] = __builtin_amdgcn_mfma_f32_16x16x32_f16(af[kt], bw[1][kt], acc[1], 0, 0, 0); \
        acc[3] = __builtin_amdgcn_mfma_f32_16x16x32_f16(af[kt], bw[3][kt], acc[3], 0, 0, 0); \
    }                                                                                \
    /* pair 0 sigmoid/tanh + write h_low(T+1) */                                     \
    _Pragma("unroll") for (int r = 0; r < 4; ++r) {                                  \
        float zf = acc[0][r];                                                        \
        float zg = acc[2][r];                                                        \
        float ef = fast_exp2(-zf);                                                   \
        float eg = fast_exp2(-fabsf(zg));                                            \
        float t1 = (zg < 0.f) ? -ef : ef;                                            \
        float cv = cst[0][r];                                                        \
        float num = fmaf(cv, eg, cv) + fmaf(-t1, eg, t1);                            \
        float den = (1.f + ef) * (1.f + eg);                                         \
        cst[0][r] = num * fast_rcp(den);                                             \
        (HWR)[(q * 4 + r) * 264 + wave * 16 + lm] = (f16)cst[0][r];                  \
    }                                                                                \
    asm volatile("s_waitcnt lgkmcnt(0)\n\ts_barrier" ::: "memory");  /* BAR_b */     \
    /* pair 1 sigmoid/tanh + write h_high(T+1); next step's low MFMAs follow */      \
    _Pragma("unroll") for (int r = 0; r < 4; ++r) {                                  \
        float zf = acc[1][r];                                                        \
        float zg = acc[3][r];                                                        \
        float ef = fast_exp2(-zf);                                                   \
        float eg = fast_exp2(-fabsf(zg));                                            \
        float t1 = (zg < 0.f) ? -ef : ef;                                            \
        float cv = cst[1][r];                                                        \
        float num = fmaf(cv, eg, cv) + fmaf(-t1, eg, t1);                            \
        float den = (1.f + ef) * (1.f + eg);                                         \
        cst[1][r] = num * fast_rcp(den);                                             \
        (HWR)[(q * 4 + r) * 264 + (wave + 8) * 16 + lm] = (f16)cst[1][r];            \
    }                                                                                \
} while (0)

__global__ __launch_bounds__(512, 2)
void janet_fused(const float* __restrict__ x, const f16* __restrict__ kt,
                 const float* __restrict__ bias, ushort_t* __restrict__ xz,
                 const float* __restrict__ rk, const float* __restrict__ dw,
                 const float* __restrict__ db, float* __restrict__ out) {
    const int tid = threadIdx.x;
    const int wave = tid >> 6;
    const int lane = tid & 63;
    const int lm = lane & 15;
    const int q  = lane >> 4;

    if (blockIdx.x >= 16) {
        // ================= GEMM path (one 128-row x 512-col tile) =================
        const long mtile = blockIdx.x - 16;   // 0..2047
        const int wm = (wave & 1) * 64;
        const int wn = (wave >> 1) * 128;     // 0,128,256,384

        f4_t acc[4][8];
#pragma unroll
        for (int mi = 0; mi < 4; ++mi)
#pragma unroll
            for (int nj = 0; nj < 8; ++nj)
                acc[mi][nj] = (f4_t){0.f, 0.f, 0.f, 0.f};

#pragma unroll
        for (int kc = 0; kc < 4; ++kc) {
            h8_t a[4], bf[8];
#pragma unroll
            for (int mi = 0; mi < 4; ++mi) {
                const int rowm = (int)(mtile * 128) + wm + mi * 16 + lm;   // m'
                const int b  = rowm & 255;
                const int tt = rowm >> 8;
                const float* ap = x + (size_t)b * (TT * II) + (size_t)tt * II + kc * 32 + q * 8;
                f4_t p0 = *(const f4_t*)ap;
                f4_t p1 = *(const f4_t*)(ap + 4);
                h8_t tv;
                tv[0] = (f16)p0[0]; tv[1] = (f16)p0[1]; tv[2] = (f16)p0[2]; tv[3] = (f16)p0[3];
                tv[4] = (f16)p1[0]; tv[5] = (f16)p1[1]; tv[6] = (f16)p1[2]; tv[7] = (f16)p1[3];
                a[mi] = tv;
            }
#pragma unroll
            for (int nj = 0; nj < 8; ++nj) {
                const f16* bp = kt + (size_t)(wn + nj * 16 + lm) * II + kc * 32 + q * 8;
                bf[nj] = *(const h8_t*)bp;
            }
#pragma unroll
            for (int mi = 0; mi < 4; ++mi)
#pragma unroll
                for (int nj = 0; nj < 8; ++nj)
                    acc[mi][nj] = __builtin_amdgcn_mfma_f32_16x16x32_f16(a[mi], bf[nj], acc[mi][nj], 0, 0, 0);
        }

        // epilogue: C/D layout col=lane&15, row=(lane>>4)*4+reg (m89); coalesced us4 bursts
#pragma unroll
        for (int mi = 0; mi < 4; ++mi) {
            const int rowm0 = (int)(mtile * 128) + wm + mi * 16 + q * 4;
            const int t  = rowm0 >> 8;
            const int b0 = rowm0 & 255;
            const int gq = b0 >> 4;
#pragma unroll
            for (int nj = 0; nj < 8; ++nj) {
                const int col = wn + nj * 16 + lm;
                const float bv = bias[col];
                const float s  = (col < CC) ? L2E : (2.0f * L2E);
                us4_t v;
#pragma unroll
                for (int r = 0; r < 4; ++r) {
                    f16 hv = (f16)((acc[mi][nj][r] + bv) * s);
                    v[r] = *(ushort_t*)&hv;
                }
                *(us4_t*)(xz + (((size_t)t * 16 + gq) * 512 + col) * 16 + q * 4) = v;
            }
        }

        // publish tile: all block stores done (syncthreads drains vmcnt), then release.
        __syncthreads();
        if (tid == 0) {
            __hip_atomic_store(&g_flags[(int)mtile], 1u, __ATOMIC_RELEASE, __HIP_MEMORY_SCOPE_AGENT);
            __hip_atomic_fetch_add(&g_flags[2048], 1u, __ATOMIC_RELEASE, __HIP_MEMORY_SCOPE_AGENT);
        }
        return;
    }

    // ================= recurrence path (blocks 0..15) =================
    const int g = blockIdx.x;            // batch group: batches g*16 .. g*16+15
    const int gh = g >> 3;               // which half-tile of each mtile pair
    bool alldone = false;

    // resident pre-scaled recurrent weights: bw[ni][kt][j] = s * R[kt*32+q*8+j][(wave+8*ni)*16+lm]
    h8_t bw[4][8];
#pragma unroll
    for (int ni = 0; ni < 4; ++ni) {
        const float s = (ni < 2) ? L2E : (2.0f * L2E);
#pragma unroll
        for (int kt = 0; kt < 8; ++kt) {
            h8_t tv;
#pragma unroll
            for (int j = 0; j < 8; ++j)
                tv[j] = (f16)(s * rk[(size_t)(kt * 32 + q * 8 + j) * GG + (wave + 8 * ni) * 16 + lm]);
            bw[ni][kt] = tv;
        }
    }

    __shared__ __align__(16) f16 hb[2][16][264];
    f16* h0 = &hb[0][0][0];
    f16* h1 = &hb[1][0][0];
    for (int i = tid; i < 2 * 16 * 264; i += 512) ((f16*)hb)[i] = (f16)0.f;

    float cst[2][4];
#pragma unroll
    for (int ni = 0; ni < 2; ++ni)
#pragma unroll
        for (int r = 0; r < 4; ++r) cst[ni][r] = 0.f;

    // wait for t=0 and t=1 tiles of this group's half
    {
        unsigned ff;
        do { ff = __hip_atomic_load(&g_flags[gh], __ATOMIC_ACQUIRE, __HIP_MEMORY_SCOPE_AGENT);
             if (!ff) __builtin_amdgcn_s_sleep(8); } while (!ff);
        do { ff = __hip_atomic_load(&g_flags[2 + gh], __ATOMIC_ACQUIRE, __HIP_MEMORY_SCOPE_AGENT);
             if (!ff) __builtin_amdgcn_s_sleep(8); } while (!ff);
    }

    // per-thread xz base (blocked layout): value(t, b=g*16+q*4+r, col=wave*16+lm+ni*128)
    // at PB[t*131072 + ni*2048 + r]; the 4 r-values are contiguous -> dwordx2 loads.
    const ushort_t* PB = xz + (size_t)g * 8192 + (wave * 16 + lm) * 16 + q * 4;
    const ushort_t* p0 = PB + 2 * 131072;       // refill source for pf0 (t=2,4,...)
    const ushort_t* p1 = PB + 3 * 131072;       // refill source for pf1 (t=3,5,...)

    ushort_t pf0[16], pf1[16];
#pragma unroll
    for (int ni = 0; ni < 4; ++ni) {
        us4_t v0 = *(const us4_t*)(PB + ni * 2048);
        us4_t v1 = *(const us4_t*)(PB + 131072 + ni * 2048);
        pf0[ni * 4 + 0] = v0[0]; pf0[ni * 4 + 1] = v0[1];
        pf0[ni * 4 + 2] = v0[2]; pf0[ni * 4 + 3] = v0[3];
        pf1[ni * 4 + 0] = v1[0]; pf1[ni * 4 + 1] = v1[1];
        pf1[ni * 4 + 2] = v1[2]; pf1[ni * 4 + 3] = v1[3];
    }
    __syncthreads();

#pragma unroll 1
    for (int t = 0; t < TT; t += 2) {
        // chunked producer verification: once per 32 steps, wave-parallel.
        // Covers refills tau = t+2 .. t+33 (steps t .. t+31 prefetch 2 ahead).
        if (((t & 31) == 0) && !alldone) {
            unsigned cn = __hip_atomic_load(&g_flags[2048], __ATOMIC_ACQUIRE,
                                            __HIP_MEMORY_SCOPE_AGENT);
            if (cn == 2048u) {
                alldone = true;
            } else {
                const int tau0 = t + 2;
                int ntau = TT - tau0; if (ntau > 32) ntau = 32;
                if (ntau > 0) {
                    const int myi = (lane < ntau) ? lane : 0;
                    const int fidx = 2 * (tau0 + myi) + gh;
                    for (;;) {
                        unsigned ff = __hip_atomic_load(&g_flags[fidx], __ATOMIC_ACQUIRE,
                                                        __HIP_MEMORY_SCOPE_AGENT);
                        if (__all(ff != 0u)) break;
                        __builtin_amdgcn_s_sleep(16);
                    }
                }
            }
        }
        STEP(t,     pf0, p0, h0, h1);
        STEP(t + 1, pf1, p1, h1, h0);
    }

    // final dense: out[b] = h_final @ dense_w + db
    __shared__ float hf[16][256];
#pragma unroll
    for (int ni = 0; ni < 2; ++ni)
#pragma unroll
        for (int r = 0; r < 4; ++r)
            hf[q * 4 + r][(wave + 8 * ni) * 16 + lm] = cst[ni][r];
    __syncthreads();
    if (tid < 160) {
        const int bi = tid / 10, o = tid % 10;
        float acc = db[o];
#pragma unroll 8
        for (int cc = 0; cc < CC; ++cc) acc = fmaf(hf[bi][cc], dw[cc * 10 + o], acc);
        out[(g * 16 + bi) * 10 + o] = acc;
    }
}

// ---- guard ----
__global__ void ws_too_small(float* out, float wssz) {
    int i = blockIdx.x * 256 + threadIdx.x;
    if (i < BB * 10) out[i] = (i == 0) ? wssz : 0.f;
}

extern "C" void kernel_launch(void* const* d_in, const int* in_sizes, int n_in,
                              void* d_out, int out_size, void* d_ws, size_t ws_size,
                              hipStream_t stream) {
    const float* x   = (const float*)d_in[0];
    const float* kin = (const float*)d_in[1];
    const float* rk  = (const float*)d_in[2];
    const float* rb  = (const float*)d_in[3];
    const float* dw  = (const float*)d_in[4];
    const float* db  = (const float*)d_in[5];
    float* out = (float*)d_out;

    const size_t xz_bytes = (size_t)BB * TT * GG * 2;   // 268,435,456
    const size_t kt_bytes = (size_t)GG * II * 2;        // 131,072
    if (ws_size < xz_bytes + kt_bytes) {
        ws_too_small<<<10, 256, 0, stream>>>(out, (float)ws_size);
        return;
    }

    ushort_t* xz = (ushort_t*)d_ws;
    f16* kt = (f16*)((char*)d_ws + xz_bytes);

    kt_transpose<<<256, 256, 0, stream>>>(kin, kt);
    // 48KB dynamic LDS (+33KB static) -> 1 block/CU: recurrence blocks get
    // dedicated CUs; gemm blocks fill the remaining ~240 CUs concurrently.
    janet_fused<<<2064, 512, 49152, stream>>>(x, kt, rb, xz, rk, dw, db, out);
}

// Round 7
// 1427.168 us; speedup vs baseline: 1.1418x; 1.0018x over previous
//
#include <hip/hip_runtime.h>

#define BB 256
#define TT 1024
#define II 128
#define GG 512   // 2C
#define CC 256
#define L2E 1.44269504f

typedef _Float16 f16;
typedef _Float16 h8_t __attribute__((ext_vector_type(8)));
typedef _Float16 h4_t __attribute__((ext_vector_type(4)));
typedef float f4_t __attribute__((ext_vector_type(4)));
typedef unsigned short ushort_t;
typedef unsigned short us4_t __attribute__((ext_vector_type(4)));

static __device__ __forceinline__ float fast_rcp(float x) {
#if __has_builtin(__builtin_amdgcn_rcpf)
    return __builtin_amdgcn_rcpf(x);
#else
    return 1.f / x;
#endif
}
static __device__ __forceinline__ float fast_exp2(float x) {
#if __has_builtin(__builtin_amdgcn_exp2f)
    return __builtin_amdgcn_exp2f(x);
#else
    return exp2f(x);
#endif
}

// producer->consumer flags: [0..2047] per-mtile ready, [2048] completion counter.
// Zeroed by kt_transpose (kernel boundary orders it before the fused kernel).
__device__ unsigned g_flags[2049];

// ---- kernel 1: Kt[n][k] = f16(kernel[k][n])  (128x512 -> 512x128), + zero flags ----
__global__ void kt_transpose(const float* __restrict__ kin, f16* __restrict__ kt) {
    int idx = blockIdx.x * 256 + threadIdx.x;   // 65536 total
    if (idx < 2049) g_flags[idx] = 0u;
    int k = idx >> 9;
    int n = idx & 511;
    kt[n * II + k] = (f16)kin[k * GG + n];
}

// ---- fused kernel: blocks 0..15 = recurrence (dispatch first -> dedicated CUs),
//      blocks 16..2063 = xz GEMM tiles running CONCURRENTLY on the other CUs.
// xz layout: xz[((t*16 + g)*512 + col)*16 + bl], batch b = g*16 + bl.
// Consumer verifies tile flags in 32-step chunks, wave-parallel (r6, proven).
// r7: gemm path stages the x-tile through LDS with fully-coalesced 512B-segment
// loads (a tile is x[b0..b0+127][tt][:], single tt) + one f32->f16 cvt, so the
// producer saturates HBM even at 1 block/CU (2 waves/SIMD) and stops throttling
// the consumer's chunk-gate. Also removes the 4x cross-wave x re-read.
#define STEP(T, PF, PP, HRD, HWR) do {                                               \
    h8_t af[8];                                                                      \
    _Pragma("unroll") for (int kt = 0; kt < 4; ++kt)                                 \
        af[kt] = *(const h8_t*)((HRD) + lm * 264 + kt * 32 + q * 8);                 \
    f4_t acc[4];                                                                     \
    _Pragma("unroll") for (int ni = 0; ni < 4; ++ni) {                               \
        f4_t av;                                                                     \
        _Pragma("unroll") for (int r = 0; r < 4; ++r) {                              \
            ushort_t u = (PF)[ni * 4 + r];                                           \
            f16 hv = *(f16*)&u;                                                      \
            av[r] = (float)hv;                                                       \
        }                                                                            \
        acc[ni] = av;                                                                \
    }                                                                                \
    if ((T) + 2 < TT) {                                                              \
        _Pragma("unroll") for (int ni = 0; ni < 4; ++ni) {                           \
            us4_t v = *(const us4_t*)((PP) + ni * 2048);                             \
            (PF)[ni * 4 + 0] = v[0];                                                 \
            (PF)[ni * 4 + 1] = v[1];                                                 \
            (PF)[ni * 4 + 2] = v[2];                                                 \
            (PF)[ni * 4 + 3] = v[3];                                                 \
        }                                                                            \
        (PP) += 2 * 131072;                                                          \
    }                                                                                \
    /* low half: kt 0..3, pair-major */                                              \
    _Pragma("unroll") for (int kt = 0; kt < 4; ++kt) {                               \
        acc[0] = __builtin_amdgcn_mfma_f32_16x16x32_f16(af[kt], bw[0][kt], acc[0], 0, 0, 0); \
        acc[2] = __builtin_amdgcn_mfma_f32_16x16x32_f16(af[kt], bw[2][kt], acc[2], 0, 0, 0); \
    }                                                                                \
    _Pragma("unroll") for (int kt = 0; kt < 4; ++kt) {                               \
        acc[1] = __builtin_amdgcn_mfma_f32_16x16x32_f16(af[kt], bw[1][kt], acc[1], 0, 0, 0); \
        acc[3] = __builtin_amdgcn_mfma_f32_16x16x32_f16(af[kt], bw[3][kt], acc[3], 0, 0, 0); \
    }                                                                                \
    asm volatile("s_waitcnt lgkmcnt(0)\n\ts_barrier" ::: "memory");  /* BAR_a */     \
    _Pragma("unroll") for (int kt = 4; kt < 8; ++kt)                                 \
        af[kt] = *(const h8_t*)((HRD) + lm * 264 + kt * 32 + q * 8);                 \
    /* high half: kt 4..7, pair-major (acc0/2 first so valu0 can start early) */     \
    _Pragma("unroll") for (int kt = 4; kt < 8; ++kt) {                               \
        acc[0] = __builtin_amdgcn_mfma_f32_16x16x32_f16(af[kt], bw[0][kt], acc[0], 0, 0, 0); \
        acc[2] = __builtin_amdgcn_mfma_f32_16x16x32_f16(af[kt], bw[2][kt], acc[2], 0, 0, 0); \
    }                                                                                \
    _Pragma("unroll") for (int kt = 4; kt < 8; ++kt) {                               \
        acc[1] = __builtin_amdgcn_mfma_f32_16x16x32_f16(af[kt], bw[1][kt], acc[1], 0, 0, 0); \
        acc[3] = __builtin_amdgcn_mfma_f32_16x16x32_f16(af[kt], bw[3][kt], acc[3], 0, 0, 0); \
    }                                                                                \
    /* pair 0 sigmoid/tanh + write h_low(T+1) */                                     \
    _Pragma("unroll") for (int r = 0; r < 4; ++r) {                                  \
        float zf = acc[0][r];                                                        \
        float zg = acc[2][r];                                                        \
        float ef = fast_exp2(-zf);                                                   \
        float eg = fast_exp2(-fabsf(zg));                                            \
        float t1 = (zg < 0.f) ? -ef : ef;                                            \
        float cv = cst[0][r];                                                        \
        float num = fmaf(cv, eg, cv) + fmaf(-t1, eg, t1);                            \
        float den = (1.f + ef) * (1.f + eg);                                         \
        cst[0][r] = num * fast_rcp(den);                                             \
        (HWR)[(q * 4 + r) * 264 + wave * 16 + lm] = (f16)cst[0][r];                  \
    }                                                                                \
    asm volatile("s_waitcnt lgkmcnt(0)\n\ts_barrier" ::: "memory");  /* BAR_b */     \
    /* pair 1 sigmoid/tanh + write h_high(T+1); next step's low MFMAs follow */      \
    _Pragma("unroll") for (int r = 0; r < 4; ++r) {                                  \
        float zf = acc[1][r];                                                        \
        float zg = acc[3][r];                                                        \
        float ef = fast_exp2(-zf);                                                   \
        float eg = fast_exp2(-fabsf(zg));                                            \
        float t1 = (zg < 0.f) ? -ef : ef;                                            \
        float cv = cst[1][r];                                                        \
        float num = fmaf(cv, eg, cv) + fmaf(-t1, eg, t1);                            \
        float den = (1.f + ef) * (1.f + eg);                                         \
        cst[1][r] = num * fast_rcp(den);                                             \
        (HWR)[(q * 4 + r) * 264 + (wave + 8) * 16 + lm] = (f16)cst[1][r];            \
    }                                                                                \
} while (0)

__global__ __launch_bounds__(512, 2)
void janet_fused(const float* __restrict__ x, const f16* __restrict__ kt,
                 const float* __restrict__ bias, ushort_t* __restrict__ xz,
                 const float* __restrict__ rk, const float* __restrict__ dw,
                 const float* __restrict__ db, float* __restrict__ out) {
    const int tid = threadIdx.x;
    const int wave = tid >> 6;
    const int lane = tid & 63;
    const int lm = lane & 15;
    const int q  = lane >> 4;

    extern __shared__ __align__(16) f16 xs[];   // gemm path: [128][132] f16, 264 B rows

    if (blockIdx.x >= 16) {
        // ================= GEMM path (one 128-row x 512-col tile) =================
        const long mtile = blockIdx.x - 16;   // 0..2047
        const int wm = (wave & 1) * 64;
        const int wn = (wave >> 1) * 128;     // 0,128,256,384

        // tile = x[bb0 .. bb0+127][tt0][:]  (single timestep, 128 consecutive batches)
        const int tt0 = (int)(mtile >> 1);
        const int bb0 = ((int)mtile & 1) * 128;

        // ---- stage: coalesced load (2 full 512B rows per wave-inst), cvt, LDS ----
        {
            const int r0  = tid >> 5;         // 0..15  (base row)
            const int c16 = tid & 31;         // 16B chunk within row
            const float* xb = x + (size_t)tt0 * II + (size_t)c16 * 4;
#pragma unroll
            for (int j = 0; j < 8; ++j) {
                const int row = r0 + j * 16;  // 0..127
                f4_t p = *(const f4_t*)(xb + (size_t)(bb0 + row) * (TT * II));
                h4_t hv;
                hv[0] = (f16)p[0]; hv[1] = (f16)p[1]; hv[2] = (f16)p[2]; hv[3] = (f16)p[3];
                *(h4_t*)(xs + row * 132 + c16 * 4) = hv;
            }
        }
        __syncthreads();

        f4_t acc[4][8];
#pragma unroll
        for (int mi = 0; mi < 4; ++mi)
#pragma unroll
            for (int nj = 0; nj < 8; ++nj)
                acc[mi][nj] = (f4_t){0.f, 0.f, 0.f, 0.f};

#pragma unroll
        for (int kc = 0; kc < 4; ++kc) {
            h8_t a[4], bf[8];
#pragma unroll
            for (int mi = 0; mi < 4; ++mi)
                a[mi] = *(const h8_t*)(xs + (wm + mi * 16 + lm) * 132 + kc * 32 + q * 8);
#pragma unroll
            for (int nj = 0; nj < 8; ++nj) {
                const f16* bp = kt + (size_t)(wn + nj * 16 + lm) * II + kc * 32 + q * 8;
                bf[nj] = *(const h8_t*)bp;
            }
#pragma unroll
            for (int mi = 0; mi < 4; ++mi)
#pragma unroll
                for (int nj = 0; nj < 8; ++nj)
                    acc[mi][nj] = __builtin_amdgcn_mfma_f32_16x16x32_f16(a[mi], bf[nj], acc[mi][nj], 0, 0, 0);
        }

        // epilogue: C/D layout col=lane&15, row=(lane>>4)*4+reg (m89); coalesced us4 bursts
#pragma unroll
        for (int mi = 0; mi < 4; ++mi) {
            const int b0r = bb0 + wm + mi * 16 + q * 4;   // batch of reg r=0
            const int gq = b0r >> 4;
#pragma unroll
            for (int nj = 0; nj < 8; ++nj) {
                const int col = wn + nj * 16 + lm;
                const float bv = bias[col];
                const float s  = (col < CC) ? L2E : (2.0f * L2E);
                us4_t v;
#pragma unroll
                for (int r = 0; r < 4; ++r) {
                    f16 hv = (f16)((acc[mi][nj][r] + bv) * s);
                    v[r] = *(ushort_t*)&hv;
                }
                *(us4_t*)(xz + (((size_t)tt0 * 16 + gq) * 512 + col) * 16 + q * 4) = v;
            }
        }

        // publish tile: all block stores done (syncthreads drains vmcnt), then release.
        __syncthreads();
        if (tid == 0) {
            __hip_atomic_store(&g_flags[(int)mtile], 1u, __ATOMIC_RELEASE, __HIP_MEMORY_SCOPE_AGENT);
            __hip_atomic_fetch_add(&g_flags[2048], 1u, __ATOMIC_RELEASE, __HIP_MEMORY_SCOPE_AGENT);
        }
        return;
    }

    // ================= recurrence path (blocks 0..15) =================
    const int g = blockIdx.x;            // batch group: batches g*16 .. g*16+15
    const int gh = g >> 3;               // which half-tile of each mtile pair
    bool alldone = false;

    // resident pre-scaled recurrent weights: bw[ni][kt][j] = s * R[kt*32+q*8+j][(wave+8*ni)*16+lm]
    h8_t bw[4][8];
#pragma unroll
    for (int ni = 0; ni < 4; ++ni) {
        const float s = (ni < 2) ? L2E : (2.0f * L2E);
#pragma unroll
        for (int kt = 0; kt < 8; ++kt) {
            h8_t tv;
#pragma unroll
            for (int j = 0; j < 8; ++j)
                tv[j] = (f16)(s * rk[(size_t)(kt * 32 + q * 8 + j) * GG + (wave + 8 * ni) * 16 + lm]);
            bw[ni][kt] = tv;
        }
    }

    __shared__ __align__(16) f16 hb[2][16][264];
    f16* h0 = &hb[0][0][0];
    f16* h1 = &hb[1][0][0];
    for (int i = tid; i < 2 * 16 * 264; i += 512) ((f16*)hb)[i] = (f16)0.f;

    float cst[2][4];
#pragma unroll
    for (int ni = 0; ni < 2; ++ni)
#pragma unroll
        for (int r = 0; r < 4; ++r) cst[ni][r] = 0.f;

    // wait for t=0 and t=1 tiles of this group's half
    {
        unsigned ff;
        do { ff = __hip_atomic_load(&g_flags[gh], __ATOMIC_ACQUIRE, __HIP_MEMORY_SCOPE_AGENT);
             if (!ff) __builtin_amdgcn_s_sleep(8); } while (!ff);
        do { ff = __hip_atomic_load(&g_flags[2 + gh], __ATOMIC_ACQUIRE, __HIP_MEMORY_SCOPE_AGENT);
             if (!ff) __builtin_amdgcn_s_sleep(8); } while (!ff);
    }

    // per-thread xz base (blocked layout): value(t, b=g*16+q*4+r, col=wave*16+lm+ni*128)
    // at PB[t*131072 + ni*2048 + r]; the 4 r-values are contiguous -> dwordx2 loads.
    const ushort_t* PB = xz + (size_t)g * 8192 + (wave * 16 + lm) * 16 + q * 4;
    const ushort_t* p0 = PB + 2 * 131072;       // refill source for pf0 (t=2,4,...)
    const ushort_t* p1 = PB + 3 * 131072;       // refill source for pf1 (t=3,5,...)

    ushort_t pf0[16], pf1[16];
#pragma unroll
    for (int ni = 0; ni < 4; ++ni) {
        us4_t v0 = *(const us4_t*)(PB + ni * 2048);
        us4_t v1 = *(const us4_t*)(PB + 131072 + ni * 2048);
        pf0[ni * 4 + 0] = v0[0]; pf0[ni * 4 + 1] = v0[1];
        pf0[ni * 4 + 2] = v0[2]; pf0[ni * 4 + 3] = v0[3];
        pf1[ni * 4 + 0] = v1[0]; pf1[ni * 4 + 1] = v1[1];
        pf1[ni * 4 + 2] = v1[2]; pf1[ni * 4 + 3] = v1[3];
    }
    __syncthreads();

#pragma unroll 1
    for (int t = 0; t < TT; t += 2) {
        // chunked producer verification: once per 32 steps, wave-parallel.
        // Covers refills tau = t+2 .. t+33 (steps t .. t+31 prefetch 2 ahead).
        if (((t & 31) == 0) && !alldone) {
            unsigned cn = __hip_atomic_load(&g_flags[2048], __ATOMIC_ACQUIRE,
                                            __HIP_MEMORY_SCOPE_AGENT);
            if (cn == 2048u) {
                alldone = true;
            } else {
                const int tau0 = t + 2;
                int ntau = TT - tau0; if (ntau > 32) ntau = 32;
                if (ntau > 0) {
                    const int myi = (lane < ntau) ? lane : 0;
                    const int fidx = 2 * (tau0 + myi) + gh;
                    for (;;) {
                        unsigned ff = __hip_atomic_load(&g_flags[fidx], __ATOMIC_ACQUIRE,
                                                        __HIP_MEMORY_SCOPE_AGENT);
                        if (__all(ff != 0u)) break;
                        __builtin_amdgcn_s_sleep(16);
                    }
                }
            }
        }
        STEP(t,     pf0, p0, h0, h1);
        STEP(t + 1, pf1, p1, h1, h0);
    }

    // final dense: out[b] = h_final @ dense_w + db
    __shared__ float hf[16][256];
#pragma unroll
    for (int ni = 0; ni < 2; ++ni)
#pragma unroll
        for (int r = 0; r < 4; ++r)
            hf[q * 4 + r][(wave + 8 * ni) * 16 + lm] = cst[ni][r];
    __syncthreads();
    if (tid < 160) {
        const int bi = tid / 10, o = tid % 10;
        float acc = db[o];
#pragma unroll 8
        for (int cc = 0; cc < CC; ++cc) acc = fmaf(hf[bi][cc], dw[cc * 10 + o], acc);
        out[(g * 16 + bi) * 10 + o] = acc;
    }
}

// ---- guard ----
__global__ void ws_too_small(float* out, float wssz) {
    int i = blockIdx.x * 256 + threadIdx.x;
    if (i < BB * 10) out[i] = (i == 0) ? wssz : 0.f;
}

extern "C" void kernel_launch(void* const* d_in, const int* in_sizes, int n_in,
                              void* d_out, int out_size, void* d_ws, size_t ws_size,
                              hipStream_t stream) {
    const float* x   = (const float*)d_in[0];
    const float* kin = (const float*)d_in[1];
    const float* rk  = (const float*)d_in[2];
    const float* rb  = (const float*)d_in[3];
    const float* dw  = (const float*)d_in[4];
    const float* db  = (const float*)d_in[5];
    float* out = (float*)d_out;

    const size_t xz_bytes = (size_t)BB * TT * GG * 2;   // 268,435,456
    const size_t kt_bytes = (size_t)GG * II * 2;        // 131,072
    if (ws_size < xz_bytes + kt_bytes) {
        ws_too_small<<<10, 256, 0, stream>>>(out, (float)ws_size);
        return;
    }

    ushort_t* xz = (ushort_t*)d_ws;
    f16* kt = (f16*)((char*)d_ws + xz_bytes);

    kt_transpose<<<256, 256, 0, stream>>>(kin, kt);
    // 48KB dynamic LDS (+33KB static) -> 1 block/CU: recurrence blocks get
    // dedicated CUs; gemm blocks use the dynamic buffer as their x-stage.
    janet_fused<<<2064, 512, 49152, stream>>>(x, kt, rb, xz, rk, dw, db, out);
}

// Round 8
// 1405.829 us; speedup vs baseline: 1.1591x; 1.0152x over previous
//
#include <hip/hip_runtime.h>

#define BB 256
#define TT 1024
#define II 128
#define GG 512   // 2C
#define CC 256
#define L2E 1.44269504f

typedef _Float16 f16;
typedef _Float16 h8_t __attribute__((ext_vector_type(8)));
typedef _Float16 h2_t __attribute__((ext_vector_type(2)));
typedef float f4_t __attribute__((ext_vector_type(4)));
typedef unsigned short ushort_t;
typedef unsigned short us4_t __attribute__((ext_vector_type(4)));
typedef unsigned u2_t __attribute__((ext_vector_type(2)));

static __device__ __forceinline__ float fast_rcp(float x) {
#if __has_builtin(__builtin_amdgcn_rcpf)
    return __builtin_amdgcn_rcpf(x);
#else
    return 1.f / x;
#endif
}
static __device__ __forceinline__ float fast_exp2(float x) {
#if __has_builtin(__builtin_amdgcn_exp2f)
    return __builtin_amdgcn_exp2f(x);
#else
    return exp2f(x);
#endif
}

// producer->consumer flags: [0..2047] per-mtile ready, [2048] completion counter.
// Zeroed by kt_transpose (kernel boundary orders it before the fused kernel).
__device__ unsigned g_flags[2049];

// ---- kernel 1: Kt[n][k] = f16(kernel[k][n])  (128x512 -> 512x128), + zero flags ----
__global__ void kt_transpose(const float* __restrict__ kin, f16* __restrict__ kt) {
    int idx = blockIdx.x * 256 + threadIdx.x;   // 65536 total
    if (idx < 2049) g_flags[idx] = 0u;
    int k = idx >> 9;
    int n = idx & 511;
    kt[n * II + k] = (f16)kin[k * GG + n];
}

// ---- fused kernel: blocks 0..15 = recurrence (dispatch first -> dedicated CUs),
//      blocks 16..2063 = xz GEMM tiles running CONCURRENTLY on the other CUs.
// xz layout: xz[((t*16 + g)*512 + col)*16 + bl], batch b = g*16 + bl.
// Consumer verifies tile flags in 32-step chunks, wave-parallel (r6, proven).
// r8: pf prefetch buffer kept PACKED (unsigned words, 2 f16 each) -> refill is
// 8 dword movs and acc-init is 16 sdwa cvts, removing the ~16-24 inst/thread/step
// extract/insert churn of the scalar ushort[16] array (VALUBusy 52% > MfmaUtil 37%
// on active CUs says VALU is the hottest pipe in the step). Gemm path reverted to
// r6 direct-load (measured 15us faster than r7's LDS stage).
#define STEP(T, PF, PP, HRD, HWR) do {                                               \
    h8_t af[8];                                                                      \
    _Pragma("unroll") for (int kt = 0; kt < 4; ++kt)                                 \
        af[kt] = *(const h8_t*)((HRD) + lm * 264 + kt * 32 + q * 8);                 \
    f4_t acc[4];                                                                     \
    _Pragma("unroll") for (int ni = 0; ni < 4; ++ni) {                               \
        h2_t a01 = *(h2_t*)&(PF)[ni * 2];                                            \
        h2_t a23 = *(h2_t*)&(PF)[ni * 2 + 1];                                        \
        acc[ni] = (f4_t){(float)a01[0], (float)a01[1], (float)a23[0], (float)a23[1]};\
    }                                                                                \
    if ((T) + 2 < TT) {                                                              \
        _Pragma("unroll") for (int ni = 0; ni < 4; ++ni) {                           \
            u2_t v = *(const u2_t*)((PP) + ni * 2048);                               \
            (PF)[ni * 2] = v[0];                                                     \
            (PF)[ni * 2 + 1] = v[1];                                                 \
        }                                                                            \
        (PP) += 2 * 131072;                                                          \
    }                                                                                \
    /* low half: kt 0..3, pair-major */                                              \
    _Pragma("unroll") for (int kt = 0; kt < 4; ++kt) {                               \
        acc[0] = __builtin_amdgcn_mfma_f32_16x16x32_f16(af[kt], bw[0][kt], acc[0], 0, 0, 0); \
        acc[2] = __builtin_amdgcn_mfma_f32_16x16x32_f16(af[kt], bw[2][kt], acc[2], 0, 0, 0); \
    }                                                                                \
    _Pragma("unroll") for (int kt = 0; kt < 4; ++kt) {                               \
        acc[1] = __builtin_amdgcn_mfma_f32_16x16x32_f16(af[kt], bw[1][kt], acc[1], 0, 0, 0); \
        acc[3] = __builtin_amdgcn_mfma_f32_16x16x32_f16(af[kt], bw[3][kt], acc[3], 0, 0, 0); \
    }                                                                                \
    asm volatile("s_waitcnt lgkmcnt(0)\n\ts_barrier" ::: "memory");  /* BAR_a */     \
    _Pragma("unroll") for (int kt = 4; kt < 8; ++kt)                                 \
        af[kt] = *(const h8_t*)((HRD) + lm * 264 + kt * 32 + q * 8);                 \
    /* high half: kt 4..7, pair-major (acc0/2 first so valu0 can start early) */     \
    _Pragma("unroll") for (int kt = 4; kt < 8; ++kt) {                               \
        acc[0] = __builtin_amdgcn_mfma_f32_16x16x32_f16(af[kt], bw[0][kt], acc[0], 0, 0, 0); \
        acc[2] = __builtin_amdgcn_mfma_f32_16x16x32_f16(af[kt], bw[2][kt], acc[2], 0, 0, 0); \
    }                                                                                \
    _Pragma("unroll") for (int kt = 4; kt < 8; ++kt) {                               \
        acc[1] = __builtin_amdgcn_mfma_f32_16x16x32_f16(af[kt], bw[1][kt], acc[1], 0, 0, 0); \
        acc[3] = __builtin_amdgcn_mfma_f32_16x16x32_f16(af[kt], bw[3][kt], acc[3], 0, 0, 0); \
    }                                                                                \
    /* pair 0 sigmoid/tanh + write h_low(T+1) */                                     \
    _Pragma("unroll") for (int r = 0; r < 4; ++r) {                                  \
        float zf = acc[0][r];                                                        \
        float zg = acc[2][r];                                                        \
        float ef = fast_exp2(-zf);                                                   \
        float eg = fast_exp2(-fabsf(zg));                                            \
        float t1 = (zg < 0.f) ? -ef : ef;                                            \
        float cv = cst[0][r];                                                        \
        float num = fmaf(cv, eg, cv) + fmaf(-t1, eg, t1);                            \
        float den = (1.f + ef) * (1.f + eg);                                         \
        cst[0][r] = num * fast_rcp(den);                                             \
        (HWR)[(q * 4 + r) * 264 + wave * 16 + lm] = (f16)cst[0][r];                  \
    }                                                                                \
    asm volatile("s_waitcnt lgkmcnt(0)\n\ts_barrier" ::: "memory");  /* BAR_b */     \
    /* pair 1 sigmoid/tanh + write h_high(T+1); next step's low MFMAs follow */      \
    _Pragma("unroll") for (int r = 0; r < 4; ++r) {                                  \
        float zf = acc[1][r];                                                        \
        float zg = acc[3][r];                                                        \
        float ef = fast_exp2(-zf);                                                   \
        float eg = fast_exp2(-fabsf(zg));                                            \
        float t1 = (zg < 0.f) ? -ef : ef;                                            \
        float cv = cst[1][r];                                                        \
        float num = fmaf(cv, eg, cv) + fmaf(-t1, eg, t1);                            \
        float den = (1.f + ef) * (1.f + eg);                                         \
        cst[1][r] = num * fast_rcp(den);                                             \
        (HWR)[(q * 4 + r) * 264 + (wave + 8) * 16 + lm] = (f16)cst[1][r];            \
    }                                                                                \
} while (0)

__global__ __launch_bounds__(512, 2)
void janet_fused(const float* __restrict__ x, const f16* __restrict__ kt,
                 const float* __restrict__ bias, ushort_t* __restrict__ xz,
                 const float* __restrict__ rk, const float* __restrict__ dw,
                 const float* __restrict__ db, float* __restrict__ out) {
    const int tid = threadIdx.x;
    const int wave = tid >> 6;
    const int lane = tid & 63;
    const int lm = lane & 15;
    const int q  = lane >> 4;

    if (blockIdx.x >= 16) {
        // ================= GEMM path (one 128-row x 512-col tile) =================
        const long mtile = blockIdx.x - 16;   // 0..2047
        const int wm = (wave & 1) * 64;
        const int wn = (wave >> 1) * 128;     // 0,128,256,384

        f4_t acc[4][8];
#pragma unroll
        for (int mi = 0; mi < 4; ++mi)
#pragma unroll
            for (int nj = 0; nj < 8; ++nj)
                acc[mi][nj] = (f4_t){0.f, 0.f, 0.f, 0.f};

#pragma unroll
        for (int kc = 0; kc < 4; ++kc) {
            h8_t a[4], bf[8];
#pragma unroll
            for (int mi = 0; mi < 4; ++mi) {
                const int rowm = (int)(mtile * 128) + wm + mi * 16 + lm;   // m'
                const int b  = rowm & 255;
                const int tt = rowm >> 8;
                const float* ap = x + (size_t)b * (TT * II) + (size_t)tt * II + kc * 32 + q * 8;
                f4_t p0 = *(const f4_t*)ap;
                f4_t p1 = *(const f4_t*)(ap + 4);
                h8_t tv;
                tv[0] = (f16)p0[0]; tv[1] = (f16)p0[1]; tv[2] = (f16)p0[2]; tv[3] = (f16)p0[3];
                tv[4] = (f16)p1[0]; tv[5] = (f16)p1[1]; tv[6] = (f16)p1[2]; tv[7] = (f16)p1[3];
                a[mi] = tv;
            }
#pragma unroll
            for (int nj = 0; nj < 8; ++nj) {
                const f16* bp = kt + (size_t)(wn + nj * 16 + lm) * II + kc * 32 + q * 8;
                bf[nj] = *(const h8_t*)bp;
            }
#pragma unroll
            for (int mi = 0; mi < 4; ++mi)
#pragma unroll
                for (int nj = 0; nj < 8; ++nj)
                    acc[mi][nj] = __builtin_amdgcn_mfma_f32_16x16x32_f16(a[mi], bf[nj], acc[mi][nj], 0, 0, 0);
        }

        // epilogue: C/D layout col=lane&15, row=(lane>>4)*4+reg (m89); coalesced us4 bursts
#pragma unroll
        for (int mi = 0; mi < 4; ++mi) {
            const int rowm0 = (int)(mtile * 128) + wm + mi * 16 + q * 4;
            const int t  = rowm0 >> 8;
            const int b0 = rowm0 & 255;
            const int gq = b0 >> 4;
#pragma unroll
            for (int nj = 0; nj < 8; ++nj) {
                const int col = wn + nj * 16 + lm;
                const float bv = bias[col];
                const float s  = (col < CC) ? L2E : (2.0f * L2E);
                us4_t v;
#pragma unroll
                for (int r = 0; r < 4; ++r) {
                    f16 hv = (f16)((acc[mi][nj][r] + bv) * s);
                    v[r] = *(ushort_t*)&hv;
                }
                *(us4_t*)(xz + (((size_t)t * 16 + gq) * 512 + col) * 16 + q * 4) = v;
            }
        }

        // publish tile: all block stores done (syncthreads drains vmcnt), then release.
        __syncthreads();
        if (tid == 0) {
            __hip_atomic_store(&g_flags[(int)mtile], 1u, __ATOMIC_RELEASE, __HIP_MEMORY_SCOPE_AGENT);
            __hip_atomic_fetch_add(&g_flags[2048], 1u, __ATOMIC_RELEASE, __HIP_MEMORY_SCOPE_AGENT);
        }
        return;
    }

    // ================= recurrence path (blocks 0..15) =================
    const int g = blockIdx.x;            // batch group: batches g*16 .. g*16+15
    const int gh = g >> 3;               // which half-tile of each mtile pair
    bool alldone = false;

    // resident pre-scaled recurrent weights: bw[ni][kt][j] = s * R[kt*32+q*8+j][(wave+8*ni)*16+lm]
    h8_t bw[4][8];
#pragma unroll
    for (int ni = 0; ni < 4; ++ni) {
        const float s = (ni < 2) ? L2E : (2.0f * L2E);
#pragma unroll
        for (int kt = 0; kt < 8; ++kt) {
            h8_t tv;
#pragma unroll
            for (int j = 0; j < 8; ++j)
                tv[j] = (f16)(s * rk[(size_t)(kt * 32 + q * 8 + j) * GG + (wave + 8 * ni) * 16 + lm]);
            bw[ni][kt] = tv;
        }
    }

    __shared__ __align__(16) f16 hb[2][16][264];
    f16* h0 = &hb[0][0][0];
    f16* h1 = &hb[1][0][0];
    for (int i = tid; i < 2 * 16 * 264; i += 512) ((f16*)hb)[i] = (f16)0.f;

    float cst[2][4];
#pragma unroll
    for (int ni = 0; ni < 2; ++ni)
#pragma unroll
        for (int r = 0; r < 4; ++r) cst[ni][r] = 0.f;

    // wait for t=0 and t=1 tiles of this group's half
    {
        unsigned ff;
        do { ff = __hip_atomic_load(&g_flags[gh], __ATOMIC_ACQUIRE, __HIP_MEMORY_SCOPE_AGENT);
             if (!ff) __builtin_amdgcn_s_sleep(8); } while (!ff);
        do { ff = __hip_atomic_load(&g_flags[2 + gh], __ATOMIC_ACQUIRE, __HIP_MEMORY_SCOPE_AGENT);
             if (!ff) __builtin_amdgcn_s_sleep(8); } while (!ff);
    }

    // per-thread xz base (blocked layout): value(t, b=g*16+q*4+r, col=wave*16+lm+ni*128)
    // at PB[t*131072 + ni*2048 + r]; the 4 r-values are contiguous -> dword2 loads,
    // kept PACKED in unsigned words (2 f16 each) until the sdwa cvt at acc-init.
    const ushort_t* PB = xz + (size_t)g * 8192 + (wave * 16 + lm) * 16 + q * 4;
    const ushort_t* p0 = PB + 2 * 131072;       // refill source for pf0 (t=2,4,...)
    const ushort_t* p1 = PB + 3 * 131072;       // refill source for pf1 (t=3,5,...)

    unsigned pf0[8], pf1[8];
#pragma unroll
    for (int ni = 0; ni < 4; ++ni) {
        u2_t v0 = *(const u2_t*)(PB + ni * 2048);
        u2_t v1 = *(const u2_t*)(PB + 131072 + ni * 2048);
        pf0[ni * 2] = v0[0]; pf0[ni * 2 + 1] = v0[1];
        pf1[ni * 2] = v1[0]; pf1[ni * 2 + 1] = v1[1];
    }
    __syncthreads();

#pragma unroll 1
    for (int t = 0; t < TT; t += 2) {
        // chunked producer verification: once per 32 steps, wave-parallel.
        // Covers refills tau = t+2 .. t+33 (steps t .. t+31 prefetch 2 ahead).
        if (((t & 31) == 0) && !alldone) {
            unsigned cn = __hip_atomic_load(&g_flags[2048], __ATOMIC_ACQUIRE,
                                            __HIP_MEMORY_SCOPE_AGENT);
            if (cn == 2048u) {
                alldone = true;
            } else {
                const int tau0 = t + 2;
                int ntau = TT - tau0; if (ntau > 32) ntau = 32;
                if (ntau > 0) {
                    const int myi = (lane < ntau) ? lane : 0;
                    const int fidx = 2 * (tau0 + myi) + gh;
                    for (;;) {
                        unsigned ff = __hip_atomic_load(&g_flags[fidx], __ATOMIC_ACQUIRE,
                                                        __HIP_MEMORY_SCOPE_AGENT);
                        if (__all(ff != 0u)) break;
                        __builtin_amdgcn_s_sleep(16);
                    }
                }
            }
        }
        STEP(t,     pf0, p0, h0, h1);
        STEP(t + 1, pf1, p1, h1, h0);
    }

    // final dense: out[b] = h_final @ dense_w + db
    __shared__ float hf[16][256];
#pragma unroll
    for (int ni = 0; ni < 2; ++ni)
#pragma unroll
        for (int r = 0; r < 4; ++r)
            hf[q * 4 + r][(wave + 8 * ni) * 16 + lm] = cst[ni][r];
    __syncthreads();
    if (tid < 160) {
        const int bi = tid / 10, o = tid % 10;
        float acc = db[o];
#pragma unroll 8
        for (int cc = 0; cc < CC; ++cc) acc = fmaf(hf[bi][cc], dw[cc * 10 + o], acc);
        out[(g * 16 + bi) * 10 + o] = acc;
    }
}

// ---- guard ----
__global__ void ws_too_small(float* out, float wssz) {
    int i = blockIdx.x * 256 + threadIdx.x;
    if (i < BB * 10) out[i] = (i == 0) ? wssz : 0.f;
}

extern "C" void kernel_launch(void* const* d_in, const int* in_sizes, int n_in,
                              void* d_out, int out_size, void* d_ws, size_t ws_size,
                              hipStream_t stream) {
    const float* x   = (const float*)d_in[0];
    const float* kin = (const float*)d_in[1];
    const float* rk  = (const float*)d_in[2];
    const float* rb  = (const float*)d_in[3];
    const float* dw  = (const float*)d_in[4];
    const float* db  = (const float*)d_in[5];
    float* out = (float*)d_out;

    const size_t xz_bytes = (size_t)BB * TT * GG * 2;   // 268,435,456
    const size_t kt_bytes = (size_t)GG * II * 2;        // 131,072
    if (ws_size < xz_bytes + kt_bytes) {
        ws_too_small<<<10, 256, 0, stream>>>(out, (float)ws_size);
        return;
    }

    ushort_t* xz = (ushort_t*)d_ws;
    f16* kt = (f16*)((char*)d_ws + xz_bytes);

    kt_transpose<<<256, 256, 0, stream>>>(kin, kt);
    // 48KB dynamic LDS (+33KB static) -> 1 block/CU: recurrence blocks get
    // dedicated CUs; gemm blocks fill the remaining ~240 CUs concurrently.
    janet_fused<<<2064, 512, 49152, stream>>>(x, kt, rb, xz, rk, dw, db, out);
}